// Round 1
// baseline (609.657 us; speedup 1.0000x reference)
//
#include <hip/hip_runtime.h>

typedef __bf16 bf16;
typedef __bf16 bf16x4 __attribute__((ext_vector_type(4)));
typedef __bf16 bf16x8 __attribute__((ext_vector_type(8)));
typedef float f32x4 __attribute__((ext_vector_type(4)));

#define M_TOT 65536   // B*T
#define K_TOT 1024    // D_IN
#define N_TOT 512     // H1
#define T_SEQ 2048
#define NB 32

// ---------------------------------------------------------------------------
// Kernel 0a: W1 [1024,512] fp32 -> W1T [512,1024] bf16 (transposed)
// ---------------------------------------------------------------------------
__global__ __launch_bounds__(256) void transpose_w1(const float* __restrict__ W1,
                                                    bf16* __restrict__ W1T) {
    __shared__ float tile[32][33];
    const int t = threadIdx.x;
    const int k0 = blockIdx.x * 32;  // gridDim.x = 32  (K=1024)
    const int n0 = blockIdx.y * 32;  // gridDim.y = 16  (N=512)
#pragma unroll
    for (int p = 0; p < 4; p++) {
        int kl = p * 8 + (t >> 5);
        int nl = t & 31;
        tile[kl][nl] = W1[(k0 + kl) * 512 + n0 + nl];
    }
    __syncthreads();
#pragma unroll
    for (int p = 0; p < 4; p++) {
        int nl = p * 8 + (t >> 5);
        int kl = t & 31;
        W1T[(n0 + nl) * 1024 + k0 + kl] = (bf16)tile[kl][nl];
    }
}

// ---------------------------------------------------------------------------
// Kernel 0b: fold layers 2+3 (no activation between them):
//   v[h] = sum_c W2[h][c]*W3[c]  (512 floats),  v[512] = b2.W3 + b3
// ---------------------------------------------------------------------------
__global__ __launch_bounds__(512) void make_v(const float* __restrict__ W2,
                                              const float* __restrict__ b2,
                                              const float* __restrict__ W3,
                                              const float* __restrict__ b3,
                                              float* __restrict__ v) {
    const int t = threadIdx.x;  // 0..511
    float s = 0.f;
#pragma unroll
    for (int c = 0; c < 32; c++) s += W2[t * 32 + c] * W3[c];
    v[t] = s;
    if (t == 0) {
        float cc = b3[0];
        for (int c = 0; c < 32; c++) cc += b2[c] * W3[c];
        v[512] = cc;
    }
}

// ---------------------------------------------------------------------------
// Kernel 1: H1 = relu(A @ W1 + b1), bf16 MFMA 16x16x32, tile 128x128, BK=64.
// 256 threads = 4 waves in 2x2; each wave does 64x64 via 4x4 MFMA frags.
// LDS layout XOR-swizzled in 16B chunks to keep ds_read_b128 conflict-free.
// ---------------------------------------------------------------------------
__device__ __forceinline__ int sw_idx(int row, int e) {  // elem index into [128][64] tile
    return row * 64 + ((((e >> 3) ^ (row & 7))) << 3) + (e & 7);
}

__global__ __launch_bounds__(256) void gemm1(const float* __restrict__ A,
                                             const bf16* __restrict__ W1T,
                                             const float* __restrict__ b1,
                                             bf16* __restrict__ H1) {
    __shared__ bf16 smem[128 * 128];  // 32 KB: As=[0,8192), Bs=[8192,16384); reused by epilogue
    bf16* As = smem;
    bf16* Bs = smem + 128 * 64;

    const int t = threadIdx.x;
    const int wave = t >> 6, lane = t & 63;
    const int q = lane >> 4, l15 = lane & 15;
    const int wm = wave >> 1, wn = wave & 1;
    const int m0 = blockIdx.y * 128;
    const int n0 = blockIdx.x * 128;

    const int arow = t >> 4;         // 0..15 (+p*16)
    const int acol = (t & 15) * 4;   // 0..60 step 4
    const int brow = t >> 3;         // 0..31 (+p*32)
    const int bcol = (t & 7) * 8;    // 0..56 step 8

    f32x4 acc[4][4] = {};

    for (int k0 = 0; k0 < K_TOT; k0 += 64) {
        float4 av[8];
        uint4 bv[4];
#pragma unroll
        for (int p = 0; p < 8; p++) {
            int row = p * 16 + arow;
            av[p] = *(const float4*)(A + (m0 + row) * K_TOT + k0 + acol);
        }
#pragma unroll
        for (int p = 0; p < 4; p++) {
            int n = p * 32 + brow;
            bv[p] = *(const uint4*)((const unsigned short*)W1T + (n0 + n) * K_TOT + k0 + bcol);
        }
        __syncthreads();  // previous iteration's MFMA reads done
#pragma unroll
        for (int p = 0; p < 8; p++) {
            int row = p * 16 + arow;
            bf16x4 pk;
            pk[0] = (bf16)av[p].x; pk[1] = (bf16)av[p].y;
            pk[2] = (bf16)av[p].z; pk[3] = (bf16)av[p].w;
            *(bf16x4*)(&As[sw_idx(row, acol)]) = pk;
        }
#pragma unroll
        for (int p = 0; p < 4; p++) {
            int n = p * 32 + brow;
            *(uint4*)(&Bs[sw_idx(n, bcol)]) = bv[p];
        }
        __syncthreads();
#pragma unroll
        for (int kk = 0; kk < 64; kk += 32) {
            bf16x8 af[4], bfr[4];
            const int e = kk + q * 8;
#pragma unroll
            for (int mi = 0; mi < 4; mi++) {
                int row = wm * 64 + mi * 16 + l15;
                af[mi] = *(const bf16x8*)(&As[sw_idx(row, e)]);
            }
#pragma unroll
            for (int ni = 0; ni < 4; ni++) {
                int n = wn * 64 + ni * 16 + l15;
                bfr[ni] = *(const bf16x8*)(&Bs[sw_idx(n, e)]);
            }
#pragma unroll
            for (int mi = 0; mi < 4; mi++)
#pragma unroll
                for (int ni = 0; ni < 4; ni++)
                    acc[mi][ni] = __builtin_amdgcn_mfma_f32_16x16x32_bf16(
                        af[mi], bfr[ni], acc[mi][ni], 0, 0, 0);
        }
    }

    // Epilogue: relu(acc + b1) -> bf16 via LDS repack for coalesced stores
    float bias[4];
#pragma unroll
    for (int ni = 0; ni < 4; ni++) bias[ni] = b1[n0 + wn * 64 + ni * 16 + l15];

    __syncthreads();
#pragma unroll
    for (int mi = 0; mi < 4; mi++)
#pragma unroll
        for (int ni = 0; ni < 4; ni++) {
            int col = wn * 64 + ni * 16 + l15;
#pragma unroll
            for (int r = 0; r < 4; r++) {
                int row = wm * 64 + mi * 16 + q * 4 + r;
                float x = acc[mi][ni][r] + bias[ni];
                smem[row * 128 + col] = (bf16)fmaxf(x, 0.f);
            }
        }
    __syncthreads();
#pragma unroll
    for (int i = t; i < 2048; i += 256) {
        int row = i >> 4;
        int col = (i & 15) * 8;
        *(uint4*)(H1 + (m0 + row) * N_TOT + n0 + col) = *(const uint4*)(&smem[row * 128 + col]);
    }
}

// ---------------------------------------------------------------------------
// Kernel 2: logits[m] = sigmoid(dot(H1[m,:], v) + c). One wave reads one full
// 1KB row per load instruction (perfect coalescing); 16 rows per wave.
// ---------------------------------------------------------------------------
__global__ __launch_bounds__(256) void dot_rows(const bf16* __restrict__ H1,
                                                const float* __restrict__ v,
                                                float* __restrict__ logits) {
    __shared__ float vsh[513];
    const int t = threadIdx.x;
    for (int i = t; i < 513; i += 256) vsh[i] = v[i];
    __syncthreads();
    const int wave = t >> 6, lane = t & 63;
    const int base = blockIdx.x * 64 + wave * 16;  // gridDim.x = 1024
    float v0[8];
#pragma unroll
    for (int j = 0; j < 8; j++) v0[j] = vsh[lane * 8 + j];
    const float c = vsh[512];
#pragma unroll 4
    for (int r = 0; r < 16; r++) {
        bf16x8 hv = *(const bf16x8*)(H1 + (base + r) * N_TOT + lane * 8);
        float s = 0.f;
#pragma unroll
        for (int j = 0; j < 8; j++) s += (float)hv[j] * v0[j];
#pragma unroll
        for (int m = 32; m >= 1; m >>= 1) s += __shfl_xor(s, m);
        if (lane == 0) logits[base + r] = 1.f / (1.f + __expf(-(s + c)));
    }
}

// ---------------------------------------------------------------------------
// Kernel 3: per-sample ragged top-k mean. Exact k-th value via binary search
// on float bit pattern (all values are sigmoid outputs in (0,1), so uint
// order == float order). Tie handling matches reference's sort+cumsum exactly.
// ---------------------------------------------------------------------------
__global__ __launch_bounds__(256) void topk_mean(const float* __restrict__ logits,
                                                 const int* __restrict__ seq_len,
                                                 float* __restrict__ out) {
    __shared__ float vals[T_SEQ];
    __shared__ int redi[4];
    __shared__ float redf[4];
    const int b = blockIdx.x, t = threadIdx.x;
    const int lane = t & 63, wave = t >> 6;
    const int L = seq_len[b];
    const int k = (L >> 4) + 1;
    const float* p = logits + b * T_SEQ;
    for (int i = t; i < L; i += 256) vals[i] = p[i];
    __syncthreads();

    unsigned lo = 0u, hi = 0x3f800000u;  // (0, 1.0]
    while (lo < hi) {
        unsigned mid = lo + ((hi - lo + 1) >> 1);
        float thr = __uint_as_float(mid);
        int cnt = 0;
        for (int i = t; i < L; i += 256) cnt += (vals[i] >= thr) ? 1 : 0;
#pragma unroll
        for (int m = 32; m >= 1; m >>= 1) cnt += __shfl_xor(cnt, m);
        if (lane == 0) redi[wave] = cnt;
        __syncthreads();
        int total = redi[0] + redi[1] + redi[2] + redi[3];
        __syncthreads();
        if (total >= k) lo = mid; else hi = mid - 1;
    }
    const float thr = __uint_as_float(lo);  // exact k-th largest value

    int cnt = 0; float sum = 0.f;
    for (int i = t; i < L; i += 256) {
        float x = vals[i];
        if (x > thr) { cnt += 1; sum += x; }
    }
#pragma unroll
    for (int m = 32; m >= 1; m >>= 1) { cnt += __shfl_xor(cnt, m); sum += __shfl_xor(sum, m); }
    if (lane == 0) { redi[wave] = cnt; redf[wave] = sum; }
    __syncthreads();
    if (t == 0) {
        int cgt = redi[0] + redi[1] + redi[2] + redi[3];
        float sgt = redf[0] + redf[1] + redf[2] + redf[3];
        out[b] = (sgt + (float)(k - cgt) * thr) / (float)k;
    }
}

// ---------------------------------------------------------------------------
extern "C" void kernel_launch(void* const* d_in, const int* in_sizes, int n_in,
                              void* d_out, int out_size, void* d_ws, size_t ws_size,
                              hipStream_t stream) {
    const float* avf = (const float*)d_in[0];
    const float* W1  = (const float*)d_in[1];
    const float* b1  = (const float*)d_in[2];
    const float* W2  = (const float*)d_in[3];
    const float* b2  = (const float*)d_in[4];
    const float* W3  = (const float*)d_in[5];
    const float* b3  = (const float*)d_in[6];
    const int* seq_len = (const int*)d_in[7];
    float* out = (float*)d_out;

    char* ws = (char*)d_ws;
    bf16*  W1T    = (bf16*)ws;                          // 1 MB
    float* v      = (float*)(ws + (1 << 20));           // 513 floats
    float* logits = (float*)(ws + (1 << 20) + 4096);    // 256 KB
    bf16*  H1     = (bf16*)(ws + (2 << 20));            // 64 MB

    transpose_w1<<<dim3(32, 16), 256, 0, stream>>>(W1, W1T);
    make_v<<<1, 512, 0, stream>>>(W2, b2, W3, b3, v);
    gemm1<<<dim3(4, 512), 256, 0, stream>>>(avf, W1T, b1, H1);
    dot_rows<<<1024, 256, 0, stream>>>(H1, v, logits);
    topk_mean<<<NB, 256, 0, stream>>>(logits, seq_len, out);
}

// Round 2
// 457.963 us; speedup vs baseline: 1.3312x; 1.3312x over previous
//
#include <hip/hip_runtime.h>

typedef __bf16 bf16;
typedef __bf16 bf16x4 __attribute__((ext_vector_type(4)));
typedef __bf16 bf16x8 __attribute__((ext_vector_type(8)));
typedef float f32x4 __attribute__((ext_vector_type(4)));

#define M_TOT 65536   // B*T
#define K_TOT 1024    // D_IN
#define N_TOT 512     // H1
#define T_SEQ 2048
#define NB 32

// ---------------------------------------------------------------------------
// async global->LDS, 16B per lane. LDS dest = wave-uniform base + lane*16.
// ---------------------------------------------------------------------------
__device__ __forceinline__ void async16(const void* g, void* l) {
    __builtin_amdgcn_global_load_lds(
        (const __attribute__((address_space(1))) unsigned int*)g,
        (__attribute__((address_space(3))) unsigned int*)l, 16, 0, 0);
}

// ---------------------------------------------------------------------------
// Kernel 0a: W1 [1024,512] fp32 -> W1T [512,1024] bf16 (transposed)
// ---------------------------------------------------------------------------
__global__ __launch_bounds__(256) void transpose_w1(const float* __restrict__ W1,
                                                    bf16* __restrict__ W1T) {
    __shared__ float tile[32][33];
    const int t = threadIdx.x;
    const int k0 = blockIdx.x * 32;  // gridDim.x = 32  (K=1024)
    const int n0 = blockIdx.y * 32;  // gridDim.y = 16  (N=512)
#pragma unroll
    for (int p = 0; p < 4; p++) {
        int kl = p * 8 + (t >> 5);
        int nl = t & 31;
        tile[kl][nl] = W1[(k0 + kl) * 512 + n0 + nl];
    }
    __syncthreads();
#pragma unroll
    for (int p = 0; p < 4; p++) {
        int nl = p * 8 + (t >> 5);
        int kl = t & 31;
        W1T[(n0 + nl) * 1024 + k0 + kl] = (bf16)tile[kl][nl];
    }
}

// ---------------------------------------------------------------------------
// Kernel 0b: fold layers 2+3 (no activation between them):
//   v[h] = sum_c W2[h][c]*W3[c]  (512 floats),  v[512] = b2.W3 + b3
// ---------------------------------------------------------------------------
__global__ __launch_bounds__(512) void make_v(const float* __restrict__ W2,
                                              const float* __restrict__ b2,
                                              const float* __restrict__ W3,
                                              const float* __restrict__ b3,
                                              float* __restrict__ v) {
    const int t = threadIdx.x;  // 0..511
    float s = 0.f;
#pragma unroll
    for (int c = 0; c < 32; c++) s += W2[t * 32 + c] * W3[c];
    v[t] = s;
    if (t == 0) {
        float cc = b3[0];
        for (int c = 0; c < 32; c++) cc += b2[c] * W3[c];
        v[512] = cc;
    }
}

// ---------------------------------------------------------------------------
// Kernel 1 (fused): per block: 128 rows x FULL N=512.
//   logits[m] = sigmoid( sum_h relu((A@W1)[m,h] + b1[h]) * v[h] + v[512] )
// 512 threads = 8 waves (wm 0..1 x wn 0..3); wave tile 64x128 (mi4 x ni8).
// A read exactly once from HBM. B (W1T bf16, 1MB) streamed via
// global_load_lds with XOR swizzle applied on the GLOBAL source address so
// the wave-uniform-base constraint is satisfied and ds_read_b128 is
// conflict-free. No H1 materialization, no atomics.
// ---------------------------------------------------------------------------
__device__ __forceinline__ int sw_idx(int row, int e) {  // elem idx into [row][64]
    return row * 64 + ((((e >> 3) ^ (row & 7))) << 3) + (e & 7);
}

__global__ __launch_bounds__(512, 1) void gemm_fused(const float* __restrict__ A,
                                                     const bf16* __restrict__ W1T,
                                                     const float* __restrict__ b1,
                                                     const float* __restrict__ v,
                                                     float* __restrict__ logits) {
    __shared__ bf16 smem[(128 + 512) * 64];  // 80 KB: As [0,8192), Bs [8192,...)
    bf16* As = smem;
    bf16* Bs = smem + 128 * 64;

    const int t = threadIdx.x;
    const int wave = t >> 6, lane = t & 63;
    const int q = lane >> 4, l15 = lane & 15;
    const int wm = wave >> 2, wn = wave & 3;     // 2 x 4 wave grid
    const int m0 = blockIdx.x * 128;

    // A staging: thread t -> row t>>2, elems e0 = (t&3)*16 .. +15
    const int arow = t >> 2;
    const int ae0  = (t & 3) * 16;
    const float* agp = A + (size_t)(m0 + arow) * K_TOT + ae0;

    // B async staging: wave handles n-rows [wave*64, wave*64+64), 8 rows/issue.
    // lane -> n-row (base + lane>>3), 16B chunk = (lane&7) XOR ((lane>>3)&7)
    const int bl_row   = wave * 64 + (lane >> 3);
    const int bl_chunk = (lane & 7) ^ ((lane >> 3) & 7);
    const bf16* bgp = W1T + (size_t)bl_row * K_TOT + bl_chunk * 8;

    f32x4 acc[4][8] = {};

#pragma unroll 1
    for (int k0 = 0; k0 < K_TOT; k0 += 64) {
        // A global -> VGPR (issued before barrier: overlaps prior MFMA)
        float4 av[4];
#pragma unroll
        for (int p = 0; p < 4; p++) av[p] = *(const float4*)(agp + k0 + p * 4);

        __syncthreads();  // prior iteration's LDS reads complete

        // B global -> LDS async (8 issues/wave covers 64 n-rows x 64 k)
#pragma unroll
        for (int j = 0; j < 8; j++)
            async16(bgp + k0 + (size_t)j * 8 * K_TOT,
                    Bs + (wave * 64 + j * 8) * 64);

        // A cvt fp32->bf16 + swizzled LDS write (two 16B stores)
        {
            bf16x8 c0, c1;
            c0[0] = (bf16)av[0].x; c0[1] = (bf16)av[0].y;
            c0[2] = (bf16)av[0].z; c0[3] = (bf16)av[0].w;
            c0[4] = (bf16)av[1].x; c0[5] = (bf16)av[1].y;
            c0[6] = (bf16)av[1].z; c0[7] = (bf16)av[1].w;
            c1[0] = (bf16)av[2].x; c1[1] = (bf16)av[2].y;
            c1[2] = (bf16)av[2].z; c1[3] = (bf16)av[2].w;
            c1[4] = (bf16)av[3].x; c1[5] = (bf16)av[3].y;
            c1[6] = (bf16)av[3].z; c1[7] = (bf16)av[3].w;
            *(bf16x8*)(&As[sw_idx(arow, ae0)])     = c0;
            *(bf16x8*)(&As[sw_idx(arow, ae0 + 8)]) = c1;
        }

        __syncthreads();  // drains vmcnt (incl. global_load_lds) + lgkmcnt

#pragma unroll
        for (int kk = 0; kk < 64; kk += 32) {
            const int e = kk + q * 8;
            bf16x8 af[4], bfr[8];
#pragma unroll
            for (int mi = 0; mi < 4; mi++) {
                int row = wm * 64 + mi * 16 + l15;
                af[mi] = *(const bf16x8*)(&As[sw_idx(row, e)]);
            }
#pragma unroll
            for (int ni = 0; ni < 8; ni++) {
                int n = wn * 128 + ni * 16 + l15;
                bfr[ni] = *(const bf16x8*)(&Bs[sw_idx(n, e)]);
            }
#pragma unroll
            for (int mi = 0; mi < 4; mi++)
#pragma unroll
                for (int ni = 0; ni < 8; ni++)
                    acc[mi][ni] = __builtin_amdgcn_mfma_f32_16x16x32_bf16(
                        af[mi], bfr[ni], acc[mi][ni], 0, 0, 0);
        }
    }

    // ---- Epilogue: logit[m] = sigmoid( sum_cols relu(acc + b1)*v + c ) ----
    float bb[8], vv[8];
#pragma unroll
    for (int ni = 0; ni < 8; ni++) {
        int col = wn * 128 + ni * 16 + l15;
        bb[ni] = b1[col];
        vv[ni] = v[col];
    }
    const float cconst = v[512];

    __syncthreads();               // MFMA LDS reads done; reuse smem
    float* part = (float*)smem;    // [128][4] per-row partial per wn

#pragma unroll
    for (int mi = 0; mi < 4; mi++) {
#pragma unroll
        for (int r = 0; r < 4; r++) {
            float s = 0.f;
#pragma unroll
            for (int ni = 0; ni < 8; ni++)
                s += fmaxf(acc[mi][ni][r] + bb[ni], 0.f) * vv[ni];
            // reduce over the 16 lanes sharing a row (l15)
            s += __shfl_xor(s, 1);
            s += __shfl_xor(s, 2);
            s += __shfl_xor(s, 4);
            s += __shfl_xor(s, 8);
            if (l15 == 0) {
                int row = wm * 64 + mi * 16 + q * 4 + r;
                part[row * 4 + wn] = s;
            }
        }
    }
    __syncthreads();
    if (t < 128) {
        float s = part[t * 4] + part[t * 4 + 1] + part[t * 4 + 2] + part[t * 4 + 3] + cconst;
        logits[m0 + t] = 1.f / (1.f + __expf(-s));
    }
}

// ---------------------------------------------------------------------------
// Kernel 3: per-sample ragged top-k mean. Exact k-th value via binary search
// on the float bit pattern (sigmoid outputs in (0,1): uint order == float
// order). Tie handling matches reference's sort+cumsum exactly.
// ---------------------------------------------------------------------------
__global__ __launch_bounds__(256) void topk_mean(const float* __restrict__ logits,
                                                 const int* __restrict__ seq_len,
                                                 float* __restrict__ out) {
    __shared__ float vals[T_SEQ];
    __shared__ int redi[4];
    __shared__ float redf[4];
    const int b = blockIdx.x, t = threadIdx.x;
    const int lane = t & 63, wave = t >> 6;
    const int L = seq_len[b];
    const int k = (L >> 4) + 1;
    const float* p = logits + b * T_SEQ;
    for (int i = t; i < L; i += 256) vals[i] = p[i];
    __syncthreads();

    unsigned lo = 0u, hi = 0x3f800000u;  // (0, 1.0]
    while (lo < hi) {
        unsigned mid = lo + ((hi - lo + 1) >> 1);
        float thr = __uint_as_float(mid);
        int cnt = 0;
        for (int i = t; i < L; i += 256) cnt += (vals[i] >= thr) ? 1 : 0;
#pragma unroll
        for (int m = 32; m >= 1; m >>= 1) cnt += __shfl_xor(cnt, m);
        if (lane == 0) redi[wave] = cnt;
        __syncthreads();
        int total = redi[0] + redi[1] + redi[2] + redi[3];
        __syncthreads();
        if (total >= k) lo = mid; else hi = mid - 1;
    }
    const float thr = __uint_as_float(lo);  // exact k-th largest value

    int cnt = 0; float sum = 0.f;
    for (int i = t; i < L; i += 256) {
        float x = vals[i];
        if (x > thr) { cnt += 1; sum += x; }
    }
#pragma unroll
    for (int m = 32; m >= 1; m >>= 1) { cnt += __shfl_xor(cnt, m); sum += __shfl_xor(sum, m); }
    if (lane == 0) { redi[wave] = cnt; redf[wave] = sum; }
    __syncthreads();
    if (t == 0) {
        int cgt = redi[0] + redi[1] + redi[2] + redi[3];
        float sgt = redf[0] + redf[1] + redf[2] + redf[3];
        out[b] = (sgt + (float)(k - cgt) * thr) / (float)k;
    }
}

// ---------------------------------------------------------------------------
extern "C" void kernel_launch(void* const* d_in, const int* in_sizes, int n_in,
                              void* d_out, int out_size, void* d_ws, size_t ws_size,
                              hipStream_t stream) {
    const float* avf = (const float*)d_in[0];
    const float* W1  = (const float*)d_in[1];
    const float* b1  = (const float*)d_in[2];
    const float* W2  = (const float*)d_in[3];
    const float* b2  = (const float*)d_in[4];
    const float* W3  = (const float*)d_in[5];
    const float* b3  = (const float*)d_in[6];
    const int* seq_len = (const int*)d_in[7];
    float* out = (float*)d_out;

    char* ws = (char*)d_ws;
    bf16*  W1T    = (bf16*)ws;                          // 1 MB
    float* v      = (float*)(ws + (1 << 20));           // 513 floats
    float* logits = (float*)(ws + (1 << 20) + 4096);    // 256 KB

    transpose_w1<<<dim3(32, 16), 256, 0, stream>>>(W1, W1T);
    make_v<<<1, 512, 0, stream>>>(W2, b2, W3, b3, v);
    gemm_fused<<<512, 512, 0, stream>>>(avf, W1T, b1, v, logits);
    topk_mean<<<NB, 256, 0, stream>>>(logits, seq_len, out);
}

// Round 3
// 426.017 us; speedup vs baseline: 1.4311x; 1.0750x over previous
//
#include <hip/hip_runtime.h>

typedef __bf16 bf16;
typedef __bf16 bf16x4 __attribute__((ext_vector_type(4)));
typedef __bf16 bf16x8 __attribute__((ext_vector_type(8)));
typedef float f32x4 __attribute__((ext_vector_type(4)));

#define K_TOT 1024    // D_IN
#define N_TOT 512     // H1
#define T_SEQ 2048
#define NB 32

// ---------------------------------------------------------------------------
// async global->LDS, 16B per lane. LDS dest = wave-uniform base + lane*16.
// ---------------------------------------------------------------------------
__device__ __forceinline__ void async16(const void* g, void* l) {
    __builtin_amdgcn_global_load_lds(
        (const __attribute__((address_space(1))) unsigned int*)g,
        (__attribute__((address_space(3))) unsigned int*)l, 16, 0, 0);
}

// ---------------------------------------------------------------------------
// Kernel 0a: W1 [1024,512] fp32 -> W1T [512,1024] bf16 (transposed)
// ---------------------------------------------------------------------------
__global__ __launch_bounds__(256) void transpose_w1(const float* __restrict__ W1,
                                                    bf16* __restrict__ W1T) {
    __shared__ float tile[32][33];
    const int t = threadIdx.x;
    const int k0 = blockIdx.x * 32;
    const int n0 = blockIdx.y * 32;
#pragma unroll
    for (int p = 0; p < 4; p++) {
        int kl = p * 8 + (t >> 5);
        int nl = t & 31;
        tile[kl][nl] = W1[(k0 + kl) * 512 + n0 + nl];
    }
    __syncthreads();
#pragma unroll
    for (int p = 0; p < 4; p++) {
        int nl = p * 8 + (t >> 5);
        int kl = t & 31;
        W1T[(n0 + nl) * 1024 + k0 + kl] = (bf16)tile[kl][nl];
    }
}

// ---------------------------------------------------------------------------
// Kernel 0b: fold layers 2+3 (no activation between them):
//   v[h] = sum_c W2[h][c]*W3[c]  (512 floats),  v[512] = b2.W3 + b3
// ---------------------------------------------------------------------------
__global__ __launch_bounds__(512) void make_v(const float* __restrict__ W2,
                                              const float* __restrict__ b2,
                                              const float* __restrict__ W3,
                                              const float* __restrict__ b3,
                                              float* __restrict__ v) {
    const int t = threadIdx.x;
    float s = 0.f;
#pragma unroll
    for (int c = 0; c < 32; c++) s += W2[t * 32 + c] * W3[c];
    v[t] = s;
    if (t == 0) {
        float cc = b3[0];
        for (int c = 0; c < 32; c++) cc += b2[c] * W3[c];
        v[512] = cc;
    }
}

// ---------------------------------------------------------------------------
// Kernel 1 (fused, double-buffered, ONE barrier per K-iter):
// per block: 128 rows x full N=512; logits = sigmoid(sum relu(h)*v + c).
// LDS 160 KB = 2 x (As 16 KB + Bs 64 KB). Prefetch k+1 issued right after
// the barrier, drained one full MFMA phase (~2500 cyc) later -> latency hidden
// even at 1 block/CU.
// ---------------------------------------------------------------------------
__device__ __forceinline__ int sw_idx(int row, int e) {  // elem idx into [row][64]
    return row * 64 + (((e >> 3) ^ (row & 7)) << 3) + (e & 7);
}

__global__ __launch_bounds__(512, 2) void gemm_fused(const float* __restrict__ A,
                                                     const bf16* __restrict__ W1T,
                                                     const float* __restrict__ b1,
                                                     const float* __restrict__ v,
                                                     float* __restrict__ logits) {
    __shared__ bf16 smem[2][(128 + 512) * 64];  // 2 x 80 KB = 160 KB (CU max)

    const int t = threadIdx.x;
    const int wave = t >> 6, lane = t & 63;
    const int q = lane >> 4, l15 = lane & 15;
    const int wm = wave >> 2, wn = wave & 3;   // 2 x 4 wave grid, wave tile 64x128
    const int m0 = blockIdx.x * 128;

    // A staging: thread t -> row t>>2, c = t&3. Load p: float idx c*4 + p*16.
    // Per instruction: 4 consecutive lanes cover 64 contiguous bytes of a row
    // -> 16 lines/instr in contiguous runs (vs 64 scattered lines in R2).
    const int arow = t >> 2, ac = t & 3;
    const float* agp = A + (size_t)(m0 + arow) * K_TOT + ac * 4;

    // B async staging: lane -> n-row wave*64 + (lane>>3), global 16B chunk
    // XOR-permuted so linear LDS (base + lane*16) ends up swizzled.
    const int bl_row = wave * 64 + (lane >> 3);
    const int bl_chunk = (lane & 7) ^ ((lane >> 3) & 7);
    const bf16* bgp = W1T + (size_t)bl_row * K_TOT + bl_chunk * 8;

    f32x4 acc[4][8] = {};
    float4 av[4];

    auto loadA = [&](int k0) {
#pragma unroll
        for (int p = 0; p < 4; p++) av[p] = *(const float4*)(agp + k0 + p * 16);
    };
    auto asyncB = [&](int k0, int b) {
        bf16* bs = smem[b] + 128 * 64;
#pragma unroll
        for (int j = 0; j < 8; j++)
            async16(bgp + k0 + (size_t)j * 8 * K_TOT, bs + (wave * 64 + j * 8) * 64);
    };
    auto writeA = [&](int b) {
        bf16* as = smem[b];
#pragma unroll
        for (int p = 0; p < 4; p++) {
            bf16x4 w;
            w[0] = (bf16)av[p].x; w[1] = (bf16)av[p].y;
            w[2] = (bf16)av[p].z; w[3] = (bf16)av[p].w;
            int chunk = 2 * p + (ac >> 1);                 // global 8-elem chunk
            int idx = arow * 64 + ((chunk ^ (arow & 7)) << 3) + (ac & 1) * 4;
            *(bf16x4*)(&as[idx]) = w;
        }
    };
    auto mfma_phase = [&](int b) {
        const bf16* as = smem[b];
        const bf16* bs = smem[b] + 128 * 64;
#pragma unroll
        for (int kk = 0; kk < 64; kk += 32) {
            const int e = kk + q * 8;
            bf16x8 af[4], bfv[8];
#pragma unroll
            for (int mi = 0; mi < 4; mi++)
                af[mi] = *(const bf16x8*)(&as[sw_idx(wm * 64 + mi * 16 + l15, e)]);
#pragma unroll
            for (int ni = 0; ni < 8; ni++)
                bfv[ni] = *(const bf16x8*)(&bs[sw_idx(wn * 128 + ni * 16 + l15, e)]);
#pragma unroll
            for (int mi = 0; mi < 4; mi++)
#pragma unroll
                for (int ni = 0; ni < 8; ni++)
                    acc[mi][ni] = __builtin_amdgcn_mfma_f32_16x16x32_bf16(
                        af[mi], bfv[ni], acc[mi][ni], 0, 0, 0);
        }
    };

    // ---- preload k=0 into buffer 0 ----
    loadA(0);
    asyncB(0, 0);
    writeA(0);          // compiler: vmcnt(8) -> waits A only, B stays in flight
    __syncthreads();    // drains B(0)

#pragma unroll 1
    for (int k = 0; k < 16; k++) {
        const int buf = k & 1, nxt = buf ^ 1;
        if (k < 15) {
            loadA((k + 1) * 64);     // A(k+1) -> VGPR   (overlaps MFMA below)
            asyncB((k + 1) * 64, nxt);  // B(k+1) -> LDS async
        }
        mfma_phase(buf);             // ~2500 cyc/CU: covers all load latency
        if (k < 15) writeA(nxt);     // vmcnt wait lands after MFMA -> ~free
        __syncthreads();             // single barrier per iter; drains B(k+1)
    }

    // ---- Epilogue: logit[m] = sigmoid( sum_cols relu(acc + b1)*v + c ) ----
    float bb[8], vv[8];
#pragma unroll
    for (int ni = 0; ni < 8; ni++) {
        int col = wn * 128 + ni * 16 + l15;
        bb[ni] = b1[col];
        vv[ni] = v[col];
    }
    const float cconst = v[512];

    __syncthreads();
    float* part = (float*)smem;      // [128][4] per-row partials per wn

#pragma unroll
    for (int mi = 0; mi < 4; mi++) {
#pragma unroll
        for (int r = 0; r < 4; r++) {
            float s = 0.f;
#pragma unroll
            for (int ni = 0; ni < 8; ni++)
                s += fmaxf(acc[mi][ni][r] + bb[ni], 0.f) * vv[ni];
            s += __shfl_xor(s, 1);
            s += __shfl_xor(s, 2);
            s += __shfl_xor(s, 4);
            s += __shfl_xor(s, 8);
            if (l15 == 0) {
                int row = wm * 64 + mi * 16 + q * 4 + r;
                part[row * 4 + wn] = s;
            }
        }
    }
    __syncthreads();
    if (t < 128) {
        float s = part[t * 4] + part[t * 4 + 1] + part[t * 4 + 2] + part[t * 4 + 3] + cconst;
        logits[m0 + t] = 1.f / (1.f + __expf(-s));
    }
}

// ---------------------------------------------------------------------------
// Kernel 3: per-sample ragged top-k mean (exact; binary search on float bits).
// ---------------------------------------------------------------------------
__global__ __launch_bounds__(256) void topk_mean(const float* __restrict__ logits,
                                                 const int* __restrict__ seq_len,
                                                 float* __restrict__ out) {
    __shared__ float vals[T_SEQ];
    __shared__ int redi[4];
    __shared__ float redf[4];
    const int b = blockIdx.x, t = threadIdx.x;
    const int lane = t & 63, wave = t >> 6;
    const int L = seq_len[b];
    const int k = (L >> 4) + 1;
    const float* p = logits + b * T_SEQ;
    for (int i = t; i < L; i += 256) vals[i] = p[i];
    __syncthreads();

    unsigned lo = 0u, hi = 0x3f800000u;  // (0, 1.0]
    while (lo < hi) {
        unsigned mid = lo + ((hi - lo + 1) >> 1);
        float thr = __uint_as_float(mid);
        int cnt = 0;
        for (int i = t; i < L; i += 256) cnt += (vals[i] >= thr) ? 1 : 0;
#pragma unroll
        for (int m = 32; m >= 1; m >>= 1) cnt += __shfl_xor(cnt, m);
        if (lane == 0) redi[wave] = cnt;
        __syncthreads();
        int total = redi[0] + redi[1] + redi[2] + redi[3];
        __syncthreads();
        if (total >= k) lo = mid; else hi = mid - 1;
    }
    const float thr = __uint_as_float(lo);

    int cnt = 0; float sum = 0.f;
    for (int i = t; i < L; i += 256) {
        float x = vals[i];
        if (x > thr) { cnt += 1; sum += x; }
    }
#pragma unroll
    for (int m = 32; m >= 1; m >>= 1) { cnt += __shfl_xor(cnt, m); sum += __shfl_xor(sum, m); }
    if (lane == 0) { redi[wave] = cnt; redf[wave] = sum; }
    __syncthreads();
    if (t == 0) {
        int cgt = redi[0] + redi[1] + redi[2] + redi[3];
        float sgt = redf[0] + redf[1] + redf[2] + redf[3];
        out[b] = (sgt + (float)(k - cgt) * thr) / (float)k;
    }
}

// ---------------------------------------------------------------------------
extern "C" void kernel_launch(void* const* d_in, const int* in_sizes, int n_in,
                              void* d_out, int out_size, void* d_ws, size_t ws_size,
                              hipStream_t stream) {
    const float* avf = (const float*)d_in[0];
    const float* W1  = (const float*)d_in[1];
    const float* b1  = (const float*)d_in[2];
    const float* W2  = (const float*)d_in[3];
    const float* b2  = (const float*)d_in[4];
    const float* W3  = (const float*)d_in[5];
    const float* b3  = (const float*)d_in[6];
    const int* seq_len = (const int*)d_in[7];
    float* out = (float*)d_out;

    char* ws = (char*)d_ws;
    bf16*  W1T    = (bf16*)ws;                          // 1 MB
    float* v      = (float*)(ws + (1 << 20));           // 513 floats
    float* logits = (float*)(ws + (1 << 20) + 4096);    // 256 KB

    transpose_w1<<<dim3(32, 16), 256, 0, stream>>>(W1, W1T);
    make_v<<<1, 512, 0, stream>>>(W2, b2, W3, b3, v);
    gemm_fused<<<512, 512, 0, stream>>>(avf, W1T, b1, v, logits);
    topk_mean<<<NB, 256, 0, stream>>>(logits, seq_len, out);
}